// Round 1
// baseline (417.804 us; speedup 1.0000x reference)
//
#include <hip/hip_runtime.h>
#include <hip/hip_cooperative_groups.h>

namespace cg = cooperative_groups;

#define B 8
#define XROWS 4096
#define AROWS 256
#define LC 4352        // AROWS + XROWS
#define DD 1024
#define KEEP 256
#define NBLK 256       // 1 block per CU, cooperative co-residency guaranteed
#define NTHR 1024      // 16 waves
#define P1ROWS 136     // LC / 32 chunks per batch
// n_dropped = LC - KEEP = 4096

typedef float vfloat4 __attribute__((ext_vector_type(4)));

__device__ __forceinline__ void nt_store4(const float4& v, float* p) {
    vfloat4 t = {v.x, v.y, v.z, v.w};
    __builtin_nontemporal_store(t, (vfloat4*)p);
}

__device__ __forceinline__ const float* combined_row(const float* __restrict__ x,
                                                     const float* __restrict__ act,
                                                     int b, int l) {
    return (l < AROWS) ? (act + ((size_t)b * AROWS + l) * DD)
                       : (x + ((size_t)b * XROWS + (l - AROWS)) * DD);
}

// One cooperative kernel, 5 phases, 4 grid syncs.
// Phase 1a: salience + per-block column sums (all 256 blocks, 136 rows each);
//           blocks 0-7 zero sums, blocks 8-15 zero ksum (overlapped).
// Phase 1b: flush column sums (1 atomic/thread); blocks 0-7 run radix top-k.
// Phase 2 : gather kept rows + ksum (all 256 blocks, 8 rows each).
// Phase 3 : ctx in LDS + rvec (4 e-rows per block); block 0 writes out_cold.
// Phase 4 : x_out = x + rvec broadcast (grid-stride, NT stores).
__global__ __launch_bounds__(NTHR, 4) void k_fused(
        const float* __restrict__ x, const float* __restrict__ act,
        const float* __restrict__ cold, const float* __restrict__ wsal,
        const float* __restrict__ wread,
        float* __restrict__ xout, float* __restrict__ out_active,
        float* __restrict__ out_cold,
        float* __restrict__ sal, float* __restrict__ sums,
        float* __restrict__ ksum, float* __restrict__ rvec,
        int* __restrict__ idx) {
    cg::grid_group grid = cg::this_grid();
    __shared__ __align__(16) char smem[36864];   // union across phases

    const int nb   = blockIdx.x;
    const int tid  = threadIdx.x;
    const int wave = tid >> 6;
    const int lane = tid & 63;
    const int b     = nb >> 5;      // 32 blocks per batch
    const int chunk = nb & 31;

    // ---------------- Phase 1a: salience + per-block column sums ----------
    float fsum;
    {
        const int c0 = lane * 4;
        const float4 w0 = *(const float4*)(wsal + 0 * 256 + c0);
        const float4 w1 = *(const float4*)(wsal + 1 * 256 + c0);
        const float4 w2 = *(const float4*)(wsal + 2 * 256 + c0);
        const float4 w3 = *(const float4*)(wsal + 3 * 256 + c0);

        float4 s0 = make_float4(0,0,0,0), s1 = s0, s2 = s0, s3 = s0;
        const int row0 = chunk * P1ROWS;

        for (int r = wave; r < P1ROWS; r += 16) {
            const int l = row0 + r;
            const float* rp = combined_row(x, act, b, l);
            const float4 a0 = *(const float4*)(rp + 0 * 256 + c0);
            const float4 a1 = *(const float4*)(rp + 1 * 256 + c0);
            const float4 a2 = *(const float4*)(rp + 2 * 256 + c0);
            const float4 a3 = *(const float4*)(rp + 3 * 256 + c0);
            s0.x += a0.x; s0.y += a0.y; s0.z += a0.z; s0.w += a0.w;
            s1.x += a1.x; s1.y += a1.y; s1.z += a1.z; s1.w += a1.w;
            s2.x += a2.x; s2.y += a2.y; s2.z += a2.z; s2.w += a2.w;
            s3.x += a3.x; s3.y += a3.y; s3.z += a3.z; s3.w += a3.w;
            float s = a0.x*w0.x + a0.y*w0.y + a0.z*w0.z + a0.w*w0.w
                    + a1.x*w1.x + a1.y*w1.y + a1.z*w1.z + a1.w*w1.w
                    + a2.x*w2.x + a2.y*w2.y + a2.z*w2.z + a2.w*w2.w
                    + a3.x*w3.x + a3.y*w3.y + a3.z*w3.z + a3.w*w3.w;
            #pragma unroll
            for (int m = 32; m >= 1; m >>= 1) s += __shfl_xor(s, m, 64);
            if (lane == 0) sal[b * LC + l] = s;
        }

        // two-step cross-wave reduce: 16 waves -> 8 LDS rows -> per-thread col
        float* acc = (float*)smem;               // [8][DD] = 32 KB
        if (wave < 8) {
            float* aw = acc + wave * DD;
            *(float4*)(aw + 0 * 256 + c0) = s0;
            *(float4*)(aw + 1 * 256 + c0) = s1;
            *(float4*)(aw + 2 * 256 + c0) = s2;
            *(float4*)(aw + 3 * 256 + c0) = s3;
        }
        __syncthreads();
        if (wave >= 8) {
            float* aw = acc + (wave - 8) * DD;
            float4* p0 = (float4*)(aw + 0 * 256 + c0);
            float4* p1 = (float4*)(aw + 1 * 256 + c0);
            float4* p2 = (float4*)(aw + 2 * 256 + c0);
            float4* p3 = (float4*)(aw + 3 * 256 + c0);
            float4 t0 = *p0, t1 = *p1, t2 = *p2, t3 = *p3;
            t0.x += s0.x; t0.y += s0.y; t0.z += s0.z; t0.w += s0.w;
            t1.x += s1.x; t1.y += s1.y; t1.z += s1.z; t1.w += s1.w;
            t2.x += s2.x; t2.y += s2.y; t2.z += s2.z; t2.w += s2.w;
            t3.x += s3.x; t3.y += s3.y; t3.z += s3.z; t3.w += s3.w;
            *p0 = t0; *p1 = t1; *p2 = t2; *p3 = t3;
        }
        __syncthreads();
        fsum = 0.0f;
        #pragma unroll
        for (int w = 0; w < 8; ++w) fsum += acc[w * DD + tid];

        // zero accumulators for the atomics that follow the sync
        if (nb < 8)       sums[nb * DD + tid]       = 0.0f;
        else if (nb < 16) ksum[(nb - 8) * DD + tid] = 0.0f;
    }
    grid.sync();   // ---- sync A: sal complete, sums/ksum zeroed -----------

    // ---------------- Phase 1b: flush sums; blocks 0-7 run top-k ----------
    atomicAdd(&sums[b * DD + tid], fsum);

    if (nb < 8) {
        unsigned* keys  = (unsigned*)smem;            // 4352*4 = 17408 B
        int*      hist  = (int*)(smem + 17408);       // 1024 B
        int*      wtot4 = (int*)(smem + 18432);       // 16 B
        int*      wtot16= (int*)(smem + 18448);       // 64 B
        unsigned* prefS = (unsigned*)(smem + 18512);
        int*      kremS = (int*)(smem + 18516);

        for (int i = tid; i < LC; i += NTHR) {
            unsigned u = __float_as_uint(sal[nb * LC + i]);
            keys[i] = (u & 0x80000000u) ? ~u : (u | 0x80000000u);
        }
        if (tid == 0) { *prefS = 0u; *kremS = KEEP; }
        __syncthreads();

        for (int pass = 0; pass < 4; ++pass) {
            const int shift = 24 - 8 * pass;
            if (tid < 256) hist[tid] = 0;
            __syncthreads();
            const unsigned pref = *prefS;
            const int krem = *kremS;
            for (int i = tid; i < LC; i += NTHR) {
                const unsigned k = keys[i];
                if (pass == 0 || (k >> (shift + 8)) == (pref >> (shift + 8)))
                    atomicAdd(&hist[(k >> shift) & 255], 1);
            }
            __syncthreads();
            int h = 0, cum = 0;
            if (tid < 256) {
                h = hist[tid];
                cum = h;
                #pragma unroll
                for (int off = 1; off <= 32; off <<= 1) {
                    int v = __shfl_down(cum, off, 64);
                    if (lane + off < 64) cum += v;
                }
                if (lane == 0) wtot4[wave] = cum;
            }
            __syncthreads();
            if (tid < 256) {
                for (int w2 = wave + 1; w2 < 4; ++w2) cum += wtot4[w2];
                if (cum >= krem && (cum - h) < krem) {
                    *prefS = pref | ((unsigned)tid << shift);
                    *kremS = krem - (cum - h);
                }
            }
            __syncthreads();
        }

        const unsigned T = *prefS;
        const int needEQ = *kremS;

        const int start = tid * 5;
        const int end = (start + 5 < LC) ? (start + 5) : LC;
        int gt = 0, eq = 0;
        for (int i = start; i < end; ++i) {
            const unsigned k = keys[i];
            gt += (k > T);
            eq += (k == T);
        }
        int packed = (gt << 16) | eq;
        int p = packed;
        #pragma unroll
        for (int off = 1; off <= 32; off <<= 1) {
            int v = __shfl_up(p, off, 64);
            if (lane >= off) p += v;
        }
        if (lane == 63) wtot16[wave] = p;
        __syncthreads();
        int base = 0;
        for (int w2 = 0; w2 < wave; ++w2) base += wtot16[w2];
        const int exc = p - packed + base;
        int gtB = exc >> 16;
        int eqB = exc & 0xFFFF;
        for (int i = start; i < end; ++i) {
            const unsigned k = keys[i];
            if (k > T) {
                idx[nb * KEEP + gtB + min(eqB, needEQ)] = i;
                ++gtB;
            } else if (k == T) {
                if (eqB < needEQ) idx[nb * KEEP + gtB + eqB] = i;
                ++eqB;
            }
        }
    }
    grid.sync();   // ---- sync B: sums final, idx final, ksum zeroed -------

    // ---------------- Phase 2: gather + ksum (all 256 blocks) -------------
    {
        const int q  = tid >> 8;      // quarter 0..3 (256 threads each)
        const int tq = tid & 255;
        const int c4 = tq * 4;
        float4 cs = make_float4(0,0,0,0);
        #pragma unroll
        for (int t = 0; t < 2; ++t) {
            const int rr = q + t * 4;
            const int k = (chunk << 3) + rr;          // 8 rows per block
            const int l = idx[b * KEEP + k];
            const float4 v = *(const float4*)(combined_row(x, act, b, l) + c4);
            nt_store4(v, out_active + ((size_t)b * KEEP + k) * DD + c4);
            cs.x += v.x; cs.y += v.y; cs.z += v.z; cs.w += v.w;
        }
        float* red = (float*)smem;    // [4][DD] = 16 KB
        *(float4*)(red + q * DD + c4) = cs;
        __syncthreads();
        if (q == 0) {
            float4 t0 = *(const float4*)(red + 0 * DD + c4);
            float4 t1 = *(const float4*)(red + 1 * DD + c4);
            float4 t2 = *(const float4*)(red + 2 * DD + c4);
            float4 t3 = *(const float4*)(red + 3 * DD + c4);
            float* kb = ksum + b * DD;
            atomicAdd(kb + c4 + 0, t0.x + t1.x + t2.x + t3.x);
            atomicAdd(kb + c4 + 1, t0.y + t1.y + t2.y + t3.y);
            atomicAdd(kb + c4 + 2, t0.z + t1.z + t2.z + t3.z);
            atomicAdd(kb + c4 + 3, t0.w + t1.w + t2.w + t3.w);
        }
    }
    grid.sync();   // ---- sync C: ksum final --------------------------------

    // ---------------- Phase 3: ctx + rvec (4 e per block) ------------------
    {
        float* ctx  = (float*)smem;            // [B][DD] = 32 KB
        float* part = (float*)(smem + 32768);  // [16][B] = 512 B
        #pragma unroll
        for (int bb = 0; bb < B; ++bb) {
            const float s = sums[bb * DD + tid];
            const float k = ksum[bb * DD + tid];
            const float c = cold[bb * DD + tid];
            const float cn = 0.9f * c + 0.1f * ((s - k) * (1.0f / 4096.0f));
            const float cx = k * (1.0f / 256.0f) + cn;
            ctx[bb * DD + tid] = cx;
            if (nb == 0) out_cold[bb * DD + tid] = cn;
        }
        __syncthreads();
        for (int j = 0; j < 4; ++j) {
            const int e = (nb << 2) | j;
            const float w = wread[(size_t)e * DD + tid];
            float pv[B];
            #pragma unroll
            for (int bb = 0; bb < B; ++bb) {
                float p = w * ctx[bb * DD + tid];
                #pragma unroll
                for (int m = 32; m >= 1; m >>= 1) p += __shfl_xor(p, m, 64);
                pv[bb] = p;
            }
            if (lane == 0) {
                #pragma unroll
                for (int bb = 0; bb < B; ++bb) part[wave * B + bb] = pv[bb];
            }
            __syncthreads();
            if (tid < B) {
                float r = 0.0f;
                #pragma unroll
                for (int w2 = 0; w2 < 16; ++w2) r += part[w2 * B + tid];
                rvec[tid * DD + e] = r;
            }
            __syncthreads();
        }
    }
    grid.sync();   // ---- sync D: rvec final --------------------------------

    // ---------------- Phase 4: x_out = x + rvec broadcast ------------------
    {
        const size_t total = (size_t)B * XROWS * (DD / 4);   // 8,388,608 float4s
        const float4* x4 = (const float4*)x;
        const float4* r4 = (const float4*)rvec;
        float* of = (float*)xout;
        for (size_t i = (size_t)nb * NTHR + tid; i < total;
             i += (size_t)NBLK * NTHR) {
            float4 v = x4[i];
            const int e4 = (int)(i & 255);          // DD/4 = 256
            const int bb = (int)(i >> 20);          // XROWS*DD/4 = 2^20 per batch
            const float4 r = r4[(bb << 8) | e4];
            v.x += r.x; v.y += r.y; v.z += r.z; v.w += r.w;
            nt_store4(v, of + i * 4);
        }
    }
}

extern "C" void kernel_launch(void* const* d_in, const int* in_sizes, int n_in,
                              void* d_out, int out_size, void* d_ws, size_t ws_size,
                              hipStream_t stream) {
    (void)in_sizes; (void)n_in; (void)out_size; (void)ws_size;
    const float* x     = (const float*)d_in[0];   // [B, XROWS, DD]
    const float* act   = (const float*)d_in[1];   // [B, AROWS, DD]
    const float* cold  = (const float*)d_in[2];   // [B, DD]
    const float* wsal  = (const float*)d_in[3];   // [DD]
    const float* wread = (const float*)d_in[4];   // [DD, DD]

    float* out        = (float*)d_out;
    float* xout       = out;                                   // B*XROWS*DD
    float* out_active = xout + (size_t)B * XROWS * DD;         // B*KEEP*DD
    float* out_cold   = out_active + (size_t)B * KEEP * DD;    // B*DD

    float* ws   = (float*)d_ws;
    float* sal  = ws;                   // B*LC   = 34816
    float* sums = sal + B * LC;         // B*DD   = 8192
    float* ksum = sums + B * DD;        // 8192
    float* rvec = ksum + B * DD;        // 8192
    int*   idx  = (int*)(rvec + B * DD);// B*KEEP = 2048 ints

    void* params[] = {
        (void*)&x, (void*)&act, (void*)&cold, (void*)&wsal, (void*)&wread,
        (void*)&xout, (void*)&out_active, (void*)&out_cold,
        (void*)&sal, (void*)&sums, (void*)&ksum, (void*)&rvec, (void*)&idx
    };
    hipLaunchCooperativeKernel((const void*)k_fused, dim3(NBLK), dim3(NTHR),
                               params, 0, stream);
}

// Round 2
// 306.913 us; speedup vs baseline: 1.3613x; 1.3613x over previous
//
#include <hip/hip_runtime.h>

#define B 8
#define XROWS 4096
#define AROWS 256
#define LC 4352        // AROWS + XROWS
#define DD 1024
#define KEEP 256
// n_dropped = LC - KEEP = 4096

typedef float vfloat4 __attribute__((ext_vector_type(4)));

__device__ __forceinline__ void nt_store4(const float4& v, float* p) {
    vfloat4 t = {v.x, v.y, v.z, v.w};
    __builtin_nontemporal_store(t, (vfloat4*)p);
}

__device__ __forceinline__ const float* combined_row(const float* __restrict__ x,
                                                     const float* __restrict__ act,
                                                     int b, int l) {
    return (l < AROWS) ? (act + ((size_t)b * AROWS + l) * DD)
                       : (x + ((size_t)b * XROWS + (l - AROWS)) * DD);
}

__global__ __launch_bounds__(256) void k_zero(float* __restrict__ p, int n) {
    int i = blockIdx.x * 256 + threadIdx.x;
    if (i < n) p[i] = 0.0f;
}

// Fused: salience[b,l] = combined[b,l,:].w_sal  AND  sums[b,d] += sum_l combined[b,l,d]
// grid = B * 136 blocks (32 rows each), block = 256 (4 waves; wave handles rows r=wave,wave+4,...)
// Unit-stride loads: lane i reads chunk j at row + j*256 + i*4 floats (wave = 1KB contiguous).
__global__ __launch_bounds__(256) void k_sal_sums(
        const float* __restrict__ x, const float* __restrict__ act,
        const float* __restrict__ wsal, float* __restrict__ sal,
        float* __restrict__ sums) {
    const int tid  = threadIdx.x;
    const int wave = tid >> 6;
    const int lane = tid & 63;
    const int b     = blockIdx.x / 136;
    const int chunk = blockIdx.x % 136;
    const int row0  = chunk * 32;
    const int c0 = lane * 4;       // lane's float4 within each 256-col chunk

    const float4 w0 = *(const float4*)(wsal + 0 * 256 + c0);
    const float4 w1 = *(const float4*)(wsal + 1 * 256 + c0);
    const float4 w2 = *(const float4*)(wsal + 2 * 256 + c0);
    const float4 w3 = *(const float4*)(wsal + 3 * 256 + c0);

    float4 s0 = make_float4(0,0,0,0), s1 = s0, s2 = s0, s3 = s0;

    for (int r = wave; r < 32; r += 4) {
        const int l = row0 + r;
        const float* rp = combined_row(x, act, b, l);
        const float4 a0 = *(const float4*)(rp + 0 * 256 + c0);
        const float4 a1 = *(const float4*)(rp + 1 * 256 + c0);
        const float4 a2 = *(const float4*)(rp + 2 * 256 + c0);
        const float4 a3 = *(const float4*)(rp + 3 * 256 + c0);
        s0.x += a0.x; s0.y += a0.y; s0.z += a0.z; s0.w += a0.w;
        s1.x += a1.x; s1.y += a1.y; s1.z += a1.z; s1.w += a1.w;
        s2.x += a2.x; s2.y += a2.y; s2.z += a2.z; s2.w += a2.w;
        s3.x += a3.x; s3.y += a3.y; s3.z += a3.z; s3.w += a3.w;
        float s = a0.x*w0.x + a0.y*w0.y + a0.z*w0.z + a0.w*w0.w
                + a1.x*w1.x + a1.y*w1.y + a1.z*w1.z + a1.w*w1.w
                + a2.x*w2.x + a2.y*w2.y + a2.z*w2.z + a2.w*w2.w
                + a3.x*w3.x + a3.y*w3.y + a3.z*w3.z + a3.w*w3.w;
        #pragma unroll
        for (int m = 32; m >= 1; m >>= 1) s += __shfl_xor(s, m, 64);
        if (lane == 0) sal[b * LC + l] = s;
    }

    // parallel combine: each wave owns acc[wave][*], single barrier
    __shared__ float acc[4][DD];
    float* aw = acc[wave];
    *(float4*)(aw + 0 * 256 + c0) = s0;
    *(float4*)(aw + 1 * 256 + c0) = s1;
    *(float4*)(aw + 2 * 256 + c0) = s2;
    *(float4*)(aw + 3 * 256 + c0) = s3;
    __syncthreads();
    const int col = tid * 4;
    float4 t0 = *(const float4*)(acc[0] + col);
    float4 t1 = *(const float4*)(acc[1] + col);
    float4 t2 = *(const float4*)(acc[2] + col);
    float4 t3 = *(const float4*)(acc[3] + col);
    float* sb = sums + b * DD;
    atomicAdd(sb + col + 0, t0.x + t1.x + t2.x + t3.x);
    atomicAdd(sb + col + 1, t0.y + t1.y + t2.y + t3.y);
    atomicAdd(sb + col + 2, t0.z + t1.z + t2.z + t3.z);
    atomicAdd(sb + col + 3, t0.w + t1.w + t2.w + t3.w);
}

// 8-bit histogram radix select of the KEEP-th largest key per batch + ascending
// tie-safe index compaction. grid = B, block = 1024. Also zeros ksum[b].
__global__ __launch_bounds__(1024) void k_topk(const float* __restrict__ sal,
                                               int* __restrict__ idx,
                                               float* __restrict__ ksum) {
    const int b = blockIdx.x;
    const int tid = threadIdx.x;
    const int lane = tid & 63;
    __shared__ unsigned keys[LC];
    __shared__ int hist[256];
    __shared__ int wtot4[4];
    __shared__ int wtot16[16];
    __shared__ unsigned prefS;
    __shared__ int kremS;

    if (tid < DD) ksum[b * DD + tid] = 0.0f;   // zero for k_gather's atomics

    for (int i = tid; i < LC; i += 1024) {
        unsigned u = __float_as_uint(sal[b * LC + i]);
        keys[i] = (u & 0x80000000u) ? ~u : (u | 0x80000000u);  // monotone map
    }
    if (tid == 0) { prefS = 0u; kremS = KEEP; }
    __syncthreads();

    for (int pass = 0; pass < 4; ++pass) {
        const int shift = 24 - 8 * pass;
        if (tid < 256) hist[tid] = 0;
        __syncthreads();
        const unsigned pref = prefS;
        const int krem = kremS;
        for (int i = tid; i < LC; i += 1024) {
            const unsigned k = keys[i];
            if (pass == 0 || (k >> (shift + 8)) == (pref >> (shift + 8)))
                atomicAdd(&hist[(k >> shift) & 255], 1);
        }
        __syncthreads();
        int h = 0, cum = 0;
        if (tid < 256) {
            h = hist[tid];
            cum = h;
            // suffix-inclusive within wave (bins tid..wave_end): cum(t) = #keys with byte >= t (wave-local)
            #pragma unroll
            for (int off = 1; off <= 32; off <<= 1) {
                int v = __shfl_down(cum, off, 64);
                if (lane + off < 64) cum += v;
            }
            if (lane == 0) wtot4[tid >> 6] = cum;
        }
        __syncthreads();
        if (tid < 256) {
            for (int w2 = (tid >> 6) + 1; w2 < 4; ++w2) cum += wtot4[w2];
            // selected bin: cum >= krem and count(byte > tid) = cum - h < krem
            if (cum >= krem && (cum - h) < krem) {
                prefS = pref | ((unsigned)tid << shift);
                kremS = krem - (cum - h);
            }
        }
        __syncthreads();
    }

    const unsigned T = prefS;
    const int needEQ = kremS;   // = KEEP - count(keys > T), >= 1

    // contiguous 5-wide segments per thread; block scan via wave shfl + 16 wave totals
    const int start = tid * 5;
    const int end = (start + 5 < LC) ? (start + 5) : LC;
    int gt = 0, eq = 0;
    for (int i = start; i < end; ++i) {
        const unsigned k = keys[i];
        gt += (k > T);
        eq += (k == T);
    }
    int packed = (gt << 16) | eq;
    int p = packed;
    #pragma unroll
    for (int off = 1; off <= 32; off <<= 1) {
        int v = __shfl_up(p, off, 64);
        if (lane >= off) p += v;
    }
    if (lane == 63) wtot16[tid >> 6] = p;
    __syncthreads();
    int base = 0;
    for (int w2 = 0; w2 < (tid >> 6); ++w2) base += wtot16[w2];
    const int exc = p - packed + base;
    int gtB = exc >> 16;
    int eqB = exc & 0xFFFF;
    for (int i = start; i < end; ++i) {
        const unsigned k = keys[i];
        if (k > T) {
            idx[b * KEEP + gtB + min(eqB, needEQ)] = i;
            ++gtB;
        } else if (k == T) {
            if (eqB < needEQ) idx[b * KEEP + gtB + eqB] = i;
            ++eqB;
        }
    }
}

// Gather kept rows -> new_active output (NT stores); accumulate kept column sums.
// grid = B*8 (32 rows/block), block = 256 (thread owns 4 columns)
__global__ __launch_bounds__(256) void k_gather(const float* __restrict__ x,
        const float* __restrict__ act, const int* __restrict__ idx,
        float* __restrict__ out_active, float* __restrict__ ksum) {
    const int b = blockIdx.x >> 3;
    const int chunk = blockIdx.x & 7;
    const int tid = threadIdx.x;
    const int c4 = tid * 4;
    float4 cs = make_float4(0,0,0,0);
    for (int r = 0; r < 32; ++r) {
        const int k = chunk * 32 + r;
        const int l = idx[b * KEEP + k];
        const float4 v = *(const float4*)(combined_row(x, act, b, l) + c4);
        nt_store4(v, out_active + ((size_t)b * KEEP + k) * DD + c4);
        cs.x += v.x; cs.y += v.y; cs.z += v.z; cs.w += v.w;
    }
    float* kb = ksum + b * DD;
    atomicAdd(kb + c4 + 0, cs.x);
    atomicAdd(kb + c4 + 1, cs.y);
    atomicAdd(kb + c4 + 2, cs.z);
    atomicAdd(kb + c4 + 3, cs.w);
}

// Fused ctx + read projection. grid = 256 blocks, block = 256 (4 waves).
// Each block computes full ctx[B][DD] in LDS once (block 0 writes out_cold),
// then each WAVE owns one e-row: rvec[b,e] = ctx[b,:].w_read[e,:].
// Wave-local: lane holds 16 cols (4 float4 chunks at stride 256); 6-shfl reduce.
__global__ __launch_bounds__(256) void k_read(const float* __restrict__ sums,
        const float* __restrict__ ksum, const float* __restrict__ cold,
        const float* __restrict__ wread, float* __restrict__ rvec,
        float* __restrict__ out_cold) {
    const int blk = blockIdx.x;
    const int tid = threadIdx.x;
    const int wave = tid >> 6;
    const int lane = tid & 63;
    const int c4 = tid * 4;
    __shared__ float ctxs[B][DD];

    #pragma unroll
    for (int bb = 0; bb < B; ++bb) {
        const float4 s  = *(const float4*)(sums + bb * DD + c4);
        const float4 ks = *(const float4*)(ksum + bb * DD + c4);
        const float4 cd = *(const float4*)(cold + bb * DD + c4);
        float4 cn, cx;
        cn.x = 0.9f * cd.x + 0.1f * ((s.x - ks.x) * (1.0f / 4096.0f));
        cn.y = 0.9f * cd.y + 0.1f * ((s.y - ks.y) * (1.0f / 4096.0f));
        cn.z = 0.9f * cd.z + 0.1f * ((s.z - ks.z) * (1.0f / 4096.0f));
        cn.w = 0.9f * cd.w + 0.1f * ((s.w - ks.w) * (1.0f / 4096.0f));
        cx.x = ks.x * (1.0f / 256.0f) + cn.x;
        cx.y = ks.y * (1.0f / 256.0f) + cn.y;
        cx.z = ks.z * (1.0f / 256.0f) + cn.z;
        cx.w = ks.w * (1.0f / 256.0f) + cn.w;
        *(float4*)(&ctxs[bb][c4]) = cx;
        if (blk == 0) *(float4*)(out_cold + bb * DD + c4) = cn;
    }
    __syncthreads();

    const int e = (blk << 2) | wave;
    const int l0 = lane * 4;
    const float* wr = wread + (size_t)e * DD;
    const float4 w0 = *(const float4*)(wr + 0 * 256 + l0);
    const float4 w1 = *(const float4*)(wr + 1 * 256 + l0);
    const float4 w2 = *(const float4*)(wr + 2 * 256 + l0);
    const float4 w3 = *(const float4*)(wr + 3 * 256 + l0);
    #pragma unroll
    for (int bb = 0; bb < B; ++bb) {
        const float4 c0 = *(const float4*)(&ctxs[bb][0 * 256 + l0]);
        const float4 c1 = *(const float4*)(&ctxs[bb][1 * 256 + l0]);
        const float4 c2 = *(const float4*)(&ctxs[bb][2 * 256 + l0]);
        const float4 c3 = *(const float4*)(&ctxs[bb][3 * 256 + l0]);
        float p = w0.x*c0.x + w0.y*c0.y + w0.z*c0.z + w0.w*c0.w
                + w1.x*c1.x + w1.y*c1.y + w1.z*c1.z + w1.w*c1.w
                + w2.x*c2.x + w2.y*c2.y + w2.z*c2.z + w2.w*c2.w
                + w3.x*c3.x + w3.y*c3.y + w3.z*c3.z + w3.w*c3.w;
        #pragma unroll
        for (int m = 32; m >= 1; m >>= 1) p += __shfl_xor(p, m, 64);
        if (lane == 0) rvec[bb * DD + e] = p;
    }
}

// x_out = x + rvec broadcast. Static schedule: block owns 1024 consecutive
// float4s; thread does 4 independent loads at stride 256 (same rvec entry),
// then 4 NT stores. grid = 8192, block = 256.
__global__ __launch_bounds__(256) void k_xout(const float* __restrict__ x,
        const float* __restrict__ rvec, float* __restrict__ xout) {
    const size_t base = (size_t)blockIdx.x * 1024 + threadIdx.x;   // float4 units
    const float4* x4 = (const float4*)x;
    const float4* r4 = (const float4*)rvec;
    float* of = (float*)xout;

    float4 v0 = x4[base + 0 * 256];
    float4 v1 = x4[base + 1 * 256];
    float4 v2 = x4[base + 2 * 256];
    float4 v3 = x4[base + 3 * 256];
    const int e4 = (int)(base & 255);          // DD/4 = 256; same for all 4
    const int bb = (int)(base >> 20);          // XROWS*DD/4 = 2^20 per batch
    const float4 r = r4[(bb << 8) | e4];
    v0.x += r.x; v0.y += r.y; v0.z += r.z; v0.w += r.w;
    v1.x += r.x; v1.y += r.y; v1.z += r.z; v1.w += r.w;
    v2.x += r.x; v2.y += r.y; v2.z += r.z; v2.w += r.w;
    v3.x += r.x; v3.y += r.y; v3.z += r.z; v3.w += r.w;
    nt_store4(v0, of + (base + 0 * 256) * 4);
    nt_store4(v1, of + (base + 1 * 256) * 4);
    nt_store4(v2, of + (base + 2 * 256) * 4);
    nt_store4(v3, of + (base + 3 * 256) * 4);
}

extern "C" void kernel_launch(void* const* d_in, const int* in_sizes, int n_in,
                              void* d_out, int out_size, void* d_ws, size_t ws_size,
                              hipStream_t stream) {
    (void)in_sizes; (void)n_in; (void)out_size; (void)ws_size;
    const float* x     = (const float*)d_in[0];   // [B, XROWS, DD]
    const float* act   = (const float*)d_in[1];   // [B, AROWS, DD]
    const float* cold  = (const float*)d_in[2];   // [B, DD]
    const float* wsal  = (const float*)d_in[3];   // [DD]
    const float* wread = (const float*)d_in[4];   // [DD, DD]

    float* out        = (float*)d_out;
    float* xout       = out;                                   // B*XROWS*DD
    float* out_active = xout + (size_t)B * XROWS * DD;         // B*KEEP*DD
    float* out_cold   = out_active + (size_t)B * KEEP * DD;    // B*DD

    float* ws   = (float*)d_ws;
    float* sal  = ws;                   // B*LC   = 34816
    float* sums = sal + B * LC;         // B*DD   = 8192
    float* ksum = sums + B * DD;        // 8192
    float* rvec = ksum + B * DD;        // 8192
    int*   idx  = (int*)(rvec + B * DD);// B*KEEP = 2048 ints

    k_zero<<<(B * DD + 255) / 256, 256, 0, stream>>>(sums, B * DD);
    k_sal_sums<<<B * 136, 256, 0, stream>>>(x, act, wsal, sal, sums);
    k_topk<<<B, 1024, 0, stream>>>(sal, idx, ksum);
    k_gather<<<B * 8, 256, 0, stream>>>(x, act, idx, out_active, ksum);
    k_read<<<256, 256, 0, stream>>>(sums, ksum, cold, wread, rvec, out_cold);
    k_xout<<<8192, 256, 0, stream>>>(x, rvec, xout);
}

// Round 4
// 303.086 us; speedup vs baseline: 1.3785x; 1.0126x over previous
//
#include <hip/hip_runtime.h>

#define B 8
#define XROWS 4096
#define AROWS 256
#define LC 4352        // AROWS + XROWS
#define DD 1024
#define KEEP 256
// n_dropped = LC - KEEP = 4096
// ctx = 0.9*cold + sums*(0.1/4096) + ksum*(1/256 - 0.1/4096)
//     = 0.9*cold + sums/40960 + ksum*(159/40960)
#define BETA  (1.0f / 40960.0f)
#define ALPHA (159.0f / 40960.0f)

typedef float vfloat4 __attribute__((ext_vector_type(4)));

__device__ __forceinline__ void nt_store4(const float4& v, float* p) {
    vfloat4 t = {v.x, v.y, v.z, v.w};
    __builtin_nontemporal_store(t, (vfloat4*)p);
}

__device__ __forceinline__ const float* combined_row(const float* __restrict__ x,
                                                     const float* __restrict__ act,
                                                     int b, int l) {
    return (l < AROWS) ? (act + ((size_t)b * AROWS + l) * DD)
                       : (x + ((size_t)b * XROWS + (l - AROWS)) * DD);
}

__global__ __launch_bounds__(256) void k_zero(float* __restrict__ p, int n) {
    int i = blockIdx.x * 256 + threadIdx.x;
    if (i < n) p[i] = 0.0f;
}

// Fused: radix keys[b,l] = monotone_map(combined[b,l,:].w_sal)  AND
//        sums[b,d] += sum_l combined[b,l,d]
// grid = B * 136 blocks (32 rows each), block = 256 (4 waves).
__global__ __launch_bounds__(256) void k_sal_sums(
        const float* __restrict__ x, const float* __restrict__ act,
        const float* __restrict__ wsal, unsigned* __restrict__ keysg,
        float* __restrict__ sums) {
    const int tid  = threadIdx.x;
    const int wave = tid >> 6;
    const int lane = tid & 63;
    const int b     = blockIdx.x / 136;
    const int chunk = blockIdx.x % 136;
    const int row0  = chunk * 32;
    const int c0 = lane * 4;       // lane's float4 within each 256-col chunk

    const float4 w0 = *(const float4*)(wsal + 0 * 256 + c0);
    const float4 w1 = *(const float4*)(wsal + 1 * 256 + c0);
    const float4 w2 = *(const float4*)(wsal + 2 * 256 + c0);
    const float4 w3 = *(const float4*)(wsal + 3 * 256 + c0);

    float4 s0 = make_float4(0,0,0,0), s1 = s0, s2 = s0, s3 = s0;

    for (int r = wave; r < 32; r += 4) {
        const int l = row0 + r;
        const float* rp = combined_row(x, act, b, l);
        const float4 a0 = *(const float4*)(rp + 0 * 256 + c0);
        const float4 a1 = *(const float4*)(rp + 1 * 256 + c0);
        const float4 a2 = *(const float4*)(rp + 2 * 256 + c0);
        const float4 a3 = *(const float4*)(rp + 3 * 256 + c0);
        s0.x += a0.x; s0.y += a0.y; s0.z += a0.z; s0.w += a0.w;
        s1.x += a1.x; s1.y += a1.y; s1.z += a1.z; s1.w += a1.w;
        s2.x += a2.x; s2.y += a2.y; s2.z += a2.z; s2.w += a2.w;
        s3.x += a3.x; s3.y += a3.y; s3.z += a3.z; s3.w += a3.w;
        float s = a0.x*w0.x + a0.y*w0.y + a0.z*w0.z + a0.w*w0.w
                + a1.x*w1.x + a1.y*w1.y + a1.z*w1.z + a1.w*w1.w
                + a2.x*w2.x + a2.y*w2.y + a2.z*w2.z + a2.w*w2.w
                + a3.x*w3.x + a3.y*w3.y + a3.z*w3.z + a3.w*w3.w;
        #pragma unroll
        for (int m = 32; m >= 1; m >>= 1) s += __shfl_xor(s, m, 64);
        if (lane == 0) {
            const unsigned u = __float_as_uint(s);
            keysg[b * LC + l] = (u & 0x80000000u) ? ~u : (u | 0x80000000u);
        }
    }

    // parallel combine: each wave owns acc[wave][*], single barrier
    __shared__ float acc[4][DD];
    float* aw = acc[wave];
    *(float4*)(aw + 0 * 256 + c0) = s0;
    *(float4*)(aw + 1 * 256 + c0) = s1;
    *(float4*)(aw + 2 * 256 + c0) = s2;
    *(float4*)(aw + 3 * 256 + c0) = s3;
    __syncthreads();
    const int col = tid * 4;
    float4 t0 = *(const float4*)(acc[0] + col);
    float4 t1 = *(const float4*)(acc[1] + col);
    float4 t2 = *(const float4*)(acc[2] + col);
    float4 t3 = *(const float4*)(acc[3] + col);
    float* sb = sums + b * DD;
    atomicAdd(sb + col + 0, t0.x + t1.x + t2.x + t3.x);
    atomicAdd(sb + col + 1, t0.y + t1.y + t2.y + t3.y);
    atomicAdd(sb + col + 2, t0.z + t1.z + t2.z + t3.z);
    atomicAdd(sb + col + 3, t0.w + t1.w + t2.w + t3.w);
}

// Merged: blocks 0-7 do the 8-bit radix top-KEEP select for batch nb (also
// zeroing ksum[nb]); blocks 8-263 concurrently compute the idx-independent
// GEMV  rpart[b,e] = sum_d wread[e,d]*(0.9*cold[b,d] + BETA*sums[b,d])
// on the otherwise-idle CUs. grid = 264, block = 1024.
__global__ __launch_bounds__(1024) void k_topk(const unsigned* __restrict__ keysg,
                                               const float* __restrict__ sums,
                                               const float* __restrict__ cold,
                                               const float* __restrict__ wread,
                                               int* __restrict__ idx,
                                               float* __restrict__ ksum,
                                               float* __restrict__ rpart) {
    const int nb = blockIdx.x;
    const int tid = threadIdx.x;
    const int wave = tid >> 6;
    const int lane = tid & 63;

    if (nb >= 8) {
        // ---------------- GEMV path: 4 e-rows per block, 4 waves each ------
        const int gb = nb - 8;            // 0..255
        const int el = wave >> 2;          // 0..3
        const int q  = wave & 3;           // column quarter
        const int e  = (gb << 2) | el;
        const int c0 = (q << 8) | (lane << 2);
        __shared__ float gpart[4][4][B];
        const float4 w4 = *(const float4*)(wread + (size_t)e * DD + c0);
        #pragma unroll
        for (int bb = 0; bb < B; ++bb) {
            const float4 cd = *(const float4*)(cold + bb * DD + c0);
            const float4 sm = *(const float4*)(sums + bb * DD + c0);
            float p = w4.x * (0.9f * cd.x + BETA * sm.x)
                    + w4.y * (0.9f * cd.y + BETA * sm.y)
                    + w4.z * (0.9f * cd.z + BETA * sm.z)
                    + w4.w * (0.9f * cd.w + BETA * sm.w);
            #pragma unroll
            for (int m = 32; m >= 1; m >>= 1) p += __shfl_xor(p, m, 64);
            if (lane == 0) gpart[el][q][bb] = p;
        }
        __syncthreads();
        if (tid < 32) {
            const int el2 = tid >> 3;
            const int bb  = tid & 7;
            rpart[bb * DD + ((gb << 2) | el2)] =
                gpart[el2][0][bb] + gpart[el2][1][bb] +
                gpart[el2][2][bb] + gpart[el2][3][bb];
        }
        return;
    }

    // ---------------- radix-select path (blocks 0-7) -----------------------
    const int b = nb;
    __shared__ unsigned keys[LC];
    __shared__ int hist[256];
    __shared__ int wtot4[4];
    __shared__ int wtot16[16];
    __shared__ unsigned prefS;
    __shared__ int kremS;

    if (tid < DD) ksum[b * DD + tid] = 0.0f;   // zero for k_gather's atomics

    for (int i = tid; i < LC; i += 1024) keys[i] = keysg[b * LC + i];
    if (tid == 0) { prefS = 0u; kremS = KEEP; }
    __syncthreads();

    for (int pass = 0; pass < 4; ++pass) {
        const int shift = 24 - 8 * pass;
        if (tid < 256) hist[tid] = 0;
        __syncthreads();
        const unsigned pref = prefS;
        const int krem = kremS;
        for (int i = tid; i < LC; i += 1024) {
            const unsigned k = keys[i];
            if (pass == 0 || (k >> (shift + 8)) == (pref >> (shift + 8)))
                atomicAdd(&hist[(k >> shift) & 255], 1);
        }
        __syncthreads();
        int h = 0, cum = 0;
        if (tid < 256) {
            h = hist[tid];
            cum = h;
            // suffix-inclusive within wave: cum(t) = #keys with byte >= t (wave-local)
            #pragma unroll
            for (int off = 1; off <= 32; off <<= 1) {
                int v = __shfl_down(cum, off, 64);
                if (lane + off < 64) cum += v;
            }
            if (lane == 0) wtot4[tid >> 6] = cum;
        }
        __syncthreads();
        if (tid < 256) {
            for (int w2 = (tid >> 6) + 1; w2 < 4; ++w2) cum += wtot4[w2];
            // selected bin: cum >= krem and count(byte > tid) = cum - h < krem
            if (cum >= krem && (cum - h) < krem) {
                prefS = pref | ((unsigned)tid << shift);
                kremS = krem - (cum - h);
            }
        }
        __syncthreads();
    }

    const unsigned T = prefS;
    const int needEQ = kremS;   // = KEEP - count(keys > T), >= 1

    // contiguous 5-wide segments per thread; block scan via wave shfl + 16 wave totals
    const int start = tid * 5;
    const int end = (start + 5 < LC) ? (start + 5) : LC;
    int gt = 0, eq = 0;
    for (int i = start; i < end; ++i) {
        const unsigned k = keys[i];
        gt += (k > T);
        eq += (k == T);
    }
    int packed = (gt << 16) | eq;
    int p = packed;
    #pragma unroll
    for (int off = 1; off <= 32; off <<= 1) {
        int v = __shfl_up(p, off, 64);
        if (lane >= off) p += v;
    }
    if (lane == 63) wtot16[tid >> 6] = p;
    __syncthreads();
    int base = 0;
    for (int w2 = 0; w2 < (tid >> 6); ++w2) base += wtot16[w2];
    const int exc = p - packed + base;
    int gtB = exc >> 16;
    int eqB = exc & 0xFFFF;
    for (int i = start; i < end; ++i) {
        const unsigned k = keys[i];
        if (k > T) {
            idx[b * KEEP + gtB + min(eqB, needEQ)] = i;
            ++gtB;
        } else if (k == T) {
            if (eqB < needEQ) idx[b * KEEP + gtB + eqB] = i;
            ++eqB;
        }
    }
}

// Gather kept rows -> new_active output (NT stores); accumulate kept column sums.
// grid = B*16 (16 rows/block), block = 256 (thread owns 4 columns)
__global__ __launch_bounds__(256) void k_gather(const float* __restrict__ x,
        const float* __restrict__ act, const int* __restrict__ idx,
        float* __restrict__ out_active, float* __restrict__ ksum) {
    const int b = blockIdx.x >> 4;
    const int chunk = blockIdx.x & 15;
    const int tid = threadIdx.x;
    const int c4 = tid * 4;
    float4 cs = make_float4(0,0,0,0);
    #pragma unroll 4
    for (int r = 0; r < 16; ++r) {
        const int k = chunk * 16 + r;
        const int l = idx[b * KEEP + k];
        const float4 v = *(const float4*)(combined_row(x, act, b, l) + c4);
        nt_store4(v, out_active + ((size_t)b * KEEP + k) * DD + c4);
        cs.x += v.x; cs.y += v.y; cs.z += v.z; cs.w += v.w;
    }
    float* kb = ksum + b * DD;
    atomicAdd(kb + c4 + 0, cs.x);
    atomicAdd(kb + c4 + 1, cs.y);
    atomicAdd(kb + c4 + 2, cs.z);
    atomicAdd(kb + c4 + 3, cs.w);
}

// Final read projection: rvec[b,e] = rpart[b,e] + ALPHA * (wread[e,:].ksum[b,:]).
// Block 0 also writes out_cold. grid = 256 blocks, block = 256 (wave per e-row).
__global__ __launch_bounds__(256) void k_read(const float* __restrict__ ksum,
        const float* __restrict__ sums, const float* __restrict__ cold,
        const float* __restrict__ wread, const float* __restrict__ rpart,
        float* __restrict__ rvec, float* __restrict__ out_cold) {
    const int blk = blockIdx.x;
    const int tid = threadIdx.x;
    const int wave = tid >> 6;
    const int lane = tid & 63;

    if (blk == 0) {
        const int c4 = tid * 4;
        #pragma unroll
        for (int bb = 0; bb < B; ++bb) {
            const float4 s  = *(const float4*)(sums + bb * DD + c4);
            const float4 ks = *(const float4*)(ksum + bb * DD + c4);
            const float4 cd = *(const float4*)(cold + bb * DD + c4);
            float4 cn;
            cn.x = 0.9f * cd.x + (s.x - ks.x) * (1.0f / 40960.0f);
            cn.y = 0.9f * cd.y + (s.y - ks.y) * (1.0f / 40960.0f);
            cn.z = 0.9f * cd.z + (s.z - ks.z) * (1.0f / 40960.0f);
            cn.w = 0.9f * cd.w + (s.w - ks.w) * (1.0f / 40960.0f);
            *(float4*)(out_cold + bb * DD + c4) = cn;
        }
    }

    const int e = (blk << 2) | wave;
    const int l0 = lane * 4;
    const float* wr = wread + (size_t)e * DD;
    const float4 w0 = *(const float4*)(wr + 0 * 256 + l0);
    const float4 w1 = *(const float4*)(wr + 1 * 256 + l0);
    const float4 w2 = *(const float4*)(wr + 2 * 256 + l0);
    const float4 w3 = *(const float4*)(wr + 3 * 256 + l0);
    #pragma unroll
    for (int bb = 0; bb < B; ++bb) {
        const float4 k0 = *(const float4*)(ksum + bb * DD + 0 * 256 + l0);
        const float4 k1 = *(const float4*)(ksum + bb * DD + 1 * 256 + l0);
        const float4 k2 = *(const float4*)(ksum + bb * DD + 2 * 256 + l0);
        const float4 k3 = *(const float4*)(ksum + bb * DD + 3 * 256 + l0);
        float p = w0.x*k0.x + w0.y*k0.y + w0.z*k0.z + w0.w*k0.w
                + w1.x*k1.x + w1.y*k1.y + w1.z*k1.z + w1.w*k1.w
                + w2.x*k2.x + w2.y*k2.y + w2.z*k2.z + w2.w*k2.w
                + w3.x*k3.x + w3.y*k3.y + w3.z*k3.z + w3.w*k3.w;
        #pragma unroll
        for (int m = 32; m >= 1; m >>= 1) p += __shfl_xor(p, m, 64);
        if (lane == 0) rvec[bb * DD + e] = rpart[bb * DD + e] + ALPHA * p;
    }
}

// x_out = x + rvec broadcast. Static schedule: block owns 1024 consecutive
// float4s; thread does 4 independent loads at stride 256 (same rvec entry),
// then 4 NT stores. grid = 8192, block = 256.
__global__ __launch_bounds__(256) void k_xout(const float* __restrict__ x,
        const float* __restrict__ rvec, float* __restrict__ xout) {
    const size_t base = (size_t)blockIdx.x * 1024 + threadIdx.x;   // float4 units
    const float4* x4 = (const float4*)x;
    const float4* r4 = (const float4*)rvec;
    float* of = (float*)xout;

    float4 v0 = x4[base + 0 * 256];
    float4 v1 = x4[base + 1 * 256];
    float4 v2 = x4[base + 2 * 256];
    float4 v3 = x4[base + 3 * 256];
    const int e4 = (int)(base & 255);          // DD/4 = 256; same for all 4
    const int bb = (int)(base >> 20);          // XROWS*DD/4 = 2^20 per batch
    const float4 r = r4[(bb << 8) | e4];
    v0.x += r.x; v0.y += r.y; v0.z += r.z; v0.w += r.w;
    v1.x += r.x; v1.y += r.y; v1.z += r.z; v1.w += r.w;
    v2.x += r.x; v2.y += r.y; v2.z += r.z; v2.w += r.w;
    v3.x += r.x; v3.y += r.y; v3.z += r.z; v3.w += r.w;
    nt_store4(v0, of + (base + 0 * 256) * 4);
    nt_store4(v1, of + (base + 1 * 256) * 4);
    nt_store4(v2, of + (base + 2 * 256) * 4);
    nt_store4(v3, of + (base + 3 * 256) * 4);
}

extern "C" void kernel_launch(void* const* d_in, const int* in_sizes, int n_in,
                              void* d_out, int out_size, void* d_ws, size_t ws_size,
                              hipStream_t stream) {
    (void)in_sizes; (void)n_in; (void)out_size; (void)ws_size;
    const float* x     = (const float*)d_in[0];   // [B, XROWS, DD]
    const float* act   = (const float*)d_in[1];   // [B, AROWS, DD]
    const float* cold  = (const float*)d_in[2];   // [B, DD]
    const float* wsal  = (const float*)d_in[3];   // [DD]
    const float* wread = (const float*)d_in[4];   // [DD, DD]

    float* out        = (float*)d_out;
    float* xout       = out;                                   // B*XROWS*DD
    float* out_active = xout + (size_t)B * XROWS * DD;         // B*KEEP*DD
    float* out_cold   = out_active + (size_t)B * KEEP * DD;    // B*DD

    float* ws    = (float*)d_ws;
    unsigned* keysg = (unsigned*)ws;        // B*LC   = 34816
    float* sums  = ws + B * LC;             // B*DD   = 8192
    float* ksum  = sums + B * DD;           // 8192
    float* rvec  = ksum + B * DD;           // 8192
    float* rpart = rvec + B * DD;           // 8192
    int*   idx   = (int*)(rpart + B * DD);  // B*KEEP = 2048 ints

    k_zero<<<(B * DD + 255) / 256, 256, 0, stream>>>(sums, B * DD);
    k_sal_sums<<<B * 136, 256, 0, stream>>>(x, act, wsal, keysg, sums);
    k_topk<<<264, 1024, 0, stream>>>(keysg, sums, cold, wread, idx, ksum, rpart);
    k_gather<<<B * 16, 256, 0, stream>>>(x, act, idx, out_active, ksum);
    k_read<<<256, 256, 0, stream>>>(ksum, sums, cold, wread, rpart, rvec, out_cold);
    k_xout<<<8192, 256, 0, stream>>>(x, rvec, xout);
}